// Round 1
// baseline (521.268 us; speedup 1.0000x reference)
//
#include <hip/hip_runtime.h>

// Problem constants (reference: S=Q=4096, E=D=2048, all fp32 in/out)
#define S_SEQ 4096
#define Q_SEQ 4096
#define E_DIM 2048
#define D_DIM 2048

typedef __bf16 bf16;
typedef __bf16 bf16x4 __attribute__((ext_vector_type(4)));
typedef __bf16 bf16x8 __attribute__((ext_vector_type(8)));
typedef float f32x4 __attribute__((ext_vector_type(4)));

// ---------------------------------------------------------------------------
// cast fp32 -> bf16, vectorized x4
// ---------------------------------------------------------------------------
__global__ __launch_bounds__(256) void cast_f32_to_bf16(
    const float* __restrict__ in, bf16* __restrict__ out, int n4) {
  int i = blockIdx.x * 256 + threadIdx.x;
  if (i < n4) {
    float4 v = reinterpret_cast<const float4*>(in)[i];
    bf16x4 o;
    o[0] = (bf16)v.x; o[1] = (bf16)v.y; o[2] = (bf16)v.z; o[3] = (bf16)v.w;
    *reinterpret_cast<bf16x4*>(out + 4 * (size_t)i) = o;
  }
}

// ---------------------------------------------------------------------------
// async global->LDS 16B helper (wave-uniform lds base + lane*16 scatter)
// ---------------------------------------------------------------------------
__device__ __forceinline__ void async_copy16(const bf16* g, bf16* l) {
  __builtin_amdgcn_global_load_lds(
      (const __attribute__((address_space(1))) void*)g,
      (__attribute__((address_space(3))) void*)l, 16, 0, 0);
}

// ---------------------------------------------------------------------------
// GEMM: C[M,N] = A[M,K] @ B[N,K]^T (+ bias[n] if OUT_BF16)
// A,B bf16 row-major with leading dims lda/ldb. 128x128 tile, BK=32.
// 256 threads = 4 waves in 2x2; each wave: 4x4 grid of 16x16x32 MFMA.
// OUT_BF16: C is bf16 (bias added). else: C is fp32, no bias.
// ---------------------------------------------------------------------------
template <bool OUT_BF16>
__global__ __launch_bounds__(256, 2) void gemm_bt(
    const bf16* __restrict__ A, int lda,
    const bf16* __restrict__ B, int ldb,
    void* __restrict__ C, int ldc,
    const float* __restrict__ bias, int K) {
  __shared__ __align__(16) bf16 Als[128 * 32];
  __shared__ __align__(16) bf16 Bls[128 * 32];

  const int tid  = threadIdx.x;
  const int wave = tid >> 6;
  const int lane = tid & 63;
  const int quad = lane >> 4;   // 0..3
  const int lrow = lane & 15;   // 0..15
  const int mBase = blockIdx.y * 128;
  const int nBase = blockIdx.x * 128;
  const int wRow = (wave >> 1) * 64;
  const int wCol = (wave & 1) * 64;

  f32x4 acc[4][4];
#pragma unroll
  for (int i = 0; i < 4; ++i)
#pragma unroll
    for (int j = 0; j < 4; ++j) {
      f32x4 z = {0.f, 0.f, 0.f, 0.f};
      acc[i][j] = z;
    }

  for (int k0 = 0; k0 < K; k0 += 32) {
    // stage A tile: 128 rows x 32 cols bf16 = 8KB = 512 chunks of 16B
#pragma unroll
    for (int c = 0; c < 2; ++c) {
      int chunk = c * 256 + tid;
      const bf16* g = A + (size_t)(mBase + (chunk >> 2)) * lda + k0 + (chunk & 3) * 8;
      async_copy16(g, Als + (size_t)(c * 256 + wave * 64) * 8);
    }
#pragma unroll
    for (int c = 0; c < 2; ++c) {
      int chunk = c * 256 + tid;
      const bf16* g = B + (size_t)(nBase + (chunk >> 2)) * ldb + k0 + (chunk & 3) * 8;
      async_copy16(g, Bls + (size_t)(c * 256 + wave * 64) * 8);
    }
    __syncthreads();  // drains vmcnt: LDS tiles ready

    bf16x8 af[4], bfr[4];
#pragma unroll
    for (int i = 0; i < 4; ++i)
      af[i] = *(const bf16x8*)(Als + (size_t)(wRow + i * 16 + lrow) * 32 + quad * 8);
#pragma unroll
    for (int j = 0; j < 4; ++j)
      bfr[j] = *(const bf16x8*)(Bls + (size_t)(wCol + j * 16 + lrow) * 32 + quad * 8);
#pragma unroll
    for (int i = 0; i < 4; ++i)
#pragma unroll
      for (int j = 0; j < 4; ++j)
        acc[i][j] = __builtin_amdgcn_mfma_f32_16x16x32_bf16(af[i], bfr[j], acc[i][j], 0, 0, 0);
    __syncthreads();  // compute done; safe to overwrite LDS next iter
  }

  // epilogue. C/D layout (verified m89/m91): col=lane&15, row=quad*4+reg
#pragma unroll
  for (int j = 0; j < 4; ++j) {
    const int cn = nBase + wCol + j * 16 + lrow;
    float bj = 0.f;
    if (OUT_BF16) bj = bias[cn];
#pragma unroll
    for (int i = 0; i < 4; ++i) {
      const int rbase = mBase + wRow + i * 16 + quad * 4;
#pragma unroll
      for (int r = 0; r < 4; ++r) {
        if (OUT_BF16)
          ((bf16*)C)[(size_t)(rbase + r) * ldc + cn] = (bf16)(acc[i][j][r] + bj);
        else
          ((float*)C)[(size_t)(rbase + r) * ldc + cn] = acc[i][j][r];
      }
    }
  }
}

// ---------------------------------------------------------------------------
// bf16 transpose: in[S,D] -> out[D,S], 64x64 tiles via LDS
// ---------------------------------------------------------------------------
__global__ __launch_bounds__(256) void transpose_bf16(
    const bf16* __restrict__ in, bf16* __restrict__ out) {
  __shared__ bf16 tile[64][66];
  const int t = threadIdx.x;
  const int c0 = blockIdx.x * 64;  // over D
  const int r0 = blockIdx.y * 64;  // over S
  const int col = t & 63;
  const int r4 = t >> 6;
#pragma unroll
  for (int i = 0; i < 16; ++i) {
    int rr = i * 4 + r4;
    tile[rr][col] = in[(size_t)(r0 + rr) * D_DIM + c0 + col];
  }
  __syncthreads();
#pragma unroll
  for (int i = 0; i < 16; ++i) {
    int rr = i * 4 + r4;
    out[(size_t)(c0 + rr) * S_SEQ + r0 + col] = tile[col][rr];
  }
}

// ---------------------------------------------------------------------------
// row softmax: logits fp32 [Q,S] -> P bf16 written in-place over each row's
// own fp32 span (so P has row stride 2*S bf16 elements). scale applied here.
// One block (256 threads) per row; row values held in registers.
// ---------------------------------------------------------------------------
__global__ __launch_bounds__(256) void softmax_rows(
    const float* __restrict__ logits, bf16* __restrict__ P, float scale) {
  __shared__ float red[8];
  const int r = blockIdx.x;
  const int t = threadIdx.x;
  const int wid = t >> 6;
  const int lane = t & 63;
  const float* src = logits + (size_t)r * S_SEQ;

  float vals[S_SEQ / 256];
  float lmax = -3.4e38f;
#pragma unroll
  for (int i = 0; i < S_SEQ / 256; ++i) {
    vals[i] = src[t + i * 256];
    lmax = fmaxf(lmax, vals[i]);
  }
#pragma unroll
  for (int off = 32; off > 0; off >>= 1)
    lmax = fmaxf(lmax, __shfl_down(lmax, off, 64));
  if (lane == 0) red[wid] = lmax;
  __syncthreads();
  if (t == 0) red[4] = fmaxf(fmaxf(red[0], red[1]), fmaxf(red[2], red[3]));
  __syncthreads();
  const float rmax = red[4];

  float lsum = 0.f;
#pragma unroll
  for (int i = 0; i < S_SEQ / 256; ++i) {
    vals[i] = __expf((vals[i] - rmax) * scale);
    lsum += vals[i];
  }
#pragma unroll
  for (int off = 32; off > 0; off >>= 1)
    lsum += __shfl_down(lsum, off, 64);
  if (lane == 0) red[wid] = lsum;
  __syncthreads();
  if (t == 0) red[5] = red[0] + red[1] + red[2] + red[3];
  __syncthreads();
  const float inv = 1.0f / red[5];

  bf16* dst = P + (size_t)r * (2 * S_SEQ);  // overlay this row's fp32 span
#pragma unroll
  for (int i = 0; i < S_SEQ / 256; ++i)
    dst[t + i * 256] = (bf16)(vals[i] * inv);
}

// ---------------------------------------------------------------------------
// launcher
// ---------------------------------------------------------------------------
extern "C" void kernel_launch(void* const* d_in, const int* in_sizes, int n_in,
                              void* d_out, int out_size, void* d_ws, size_t ws_size,
                              hipStream_t stream) {
  const float* key   = (const float*)d_in[0];
  const float* value = (const float*)d_in[1];
  const float* query = (const float*)d_in[2];
  const float* Wk = (const float*)d_in[3];
  const float* bk = (const float*)d_in[4];
  const float* Wq = (const float*)d_in[5];
  const float* bq = (const float*)d_in[6];
  const float* Wv = (const float*)d_in[7];
  const float* bv = (const float*)d_in[8];

  const size_t MB = 1ull << 20;
  char* ws = (char*)d_ws;
  // ws layout (136 MiB total):
  //   0..48Mi   : key_bf/value_bf/query_bf   (dead after projections)
  //   48..72Mi  : Wk_bf/Wq_bf/Wv_bf          (dead after projections)
  //   72..120Mi : k_bf / q_bf / v_bf
  //   120..136Mi: vT_bf
  //   0..64Mi   : logits fp32 (reuses cast region); P bf16 overlays rows
  bf16* key_bf   = (bf16*)(ws + 0 * MB);
  bf16* value_bf = (bf16*)(ws + 16 * MB);
  bf16* query_bf = (bf16*)(ws + 32 * MB);
  bf16* Wk_bf    = (bf16*)(ws + 48 * MB);
  bf16* Wq_bf    = (bf16*)(ws + 56 * MB);
  bf16* Wv_bf    = (bf16*)(ws + 64 * MB);
  bf16* k_bf     = (bf16*)(ws + 72 * MB);
  bf16* q_bf     = (bf16*)(ws + 88 * MB);
  bf16* v_bf     = (bf16*)(ws + 104 * MB);
  bf16* vT_bf    = (bf16*)(ws + 120 * MB);
  float* logits  = (float*)(ws + 0 * MB);
  bf16* P        = (bf16*)(ws + 0 * MB);

  // 1. casts
  {
    int n4 = (S_SEQ * E_DIM) / 4;
    int g = (n4 + 255) / 256;
    cast_f32_to_bf16<<<g, 256, 0, stream>>>(key, key_bf, n4);
    cast_f32_to_bf16<<<g, 256, 0, stream>>>(value, value_bf, n4);
    cast_f32_to_bf16<<<g, 256, 0, stream>>>(query, query_bf, n4);
    int n4w = (D_DIM * E_DIM) / 4;
    int gw = (n4w + 255) / 256;
    cast_f32_to_bf16<<<gw, 256, 0, stream>>>(Wk, Wk_bf, n4w);
    cast_f32_to_bf16<<<gw, 256, 0, stream>>>(Wq, Wq_bf, n4w);
    cast_f32_to_bf16<<<gw, 256, 0, stream>>>(Wv, Wv_bf, n4w);
  }

  // 2. projections: x @ W^T + b  -> bf16 [seq, D]
  dim3 blk(256);
  dim3 gProj(D_DIM / 128, S_SEQ / 128);
  gemm_bt<true><<<gProj, blk, 0, stream>>>(key_bf, E_DIM, Wk_bf, E_DIM,
                                           (void*)k_bf, D_DIM, bk, E_DIM);
  gemm_bt<true><<<gProj, blk, 0, stream>>>(query_bf, E_DIM, Wq_bf, E_DIM,
                                           (void*)q_bf, D_DIM, bq, E_DIM);
  gemm_bt<true><<<gProj, blk, 0, stream>>>(value_bf, E_DIM, Wv_bf, E_DIM,
                                           (void*)v_bf, D_DIM, bv, E_DIM);

  // 3. v^T for the PV GEMM
  transpose_bf16<<<dim3(D_DIM / 64, S_SEQ / 64), blk, 0, stream>>>(v_bf, vT_bf);

  // 4. logits = q @ k^T (fp32, unscaled; scale folded into softmax)
  gemm_bt<false><<<dim3(S_SEQ / 128, Q_SEQ / 128), blk, 0, stream>>>(
      q_bf, D_DIM, k_bf, D_DIM, (void*)logits, S_SEQ, nullptr, D_DIM);

  // 5. softmax rows -> P bf16 (row stride 2*S over the logits region)
  const float scale = 0.022097086912079608f;  // 1/sqrt(2048)
  softmax_rows<<<Q_SEQ, blk, 0, stream>>>(logits, P, scale);

  // 6. out = P @ v  (= P @ (vT)^T), fp32 to d_out
  gemm_bt<false><<<dim3(D_DIM / 128, Q_SEQ / 128), blk, 0, stream>>>(
      P, 2 * S_SEQ, vT_bf, S_SEQ, d_out, D_DIM, nullptr, S_SEQ);
}

// Round 3
// 491.529 us; speedup vs baseline: 1.0605x; 1.0605x over previous
//
#include <hip/hip_runtime.h>

// Problem constants (reference: S=Q=4096, E=D=2048, all fp32 in/out)
#define S_SEQ 4096
#define Q_SEQ 4096
#define E_DIM 2048
#define D_DIM 2048

typedef __bf16 bf16;
typedef __bf16 bf16x4 __attribute__((ext_vector_type(4)));
typedef __bf16 bf16x8 __attribute__((ext_vector_type(8)));
typedef float f32x4 __attribute__((ext_vector_type(4)));

// ---------------------------------------------------------------------------
// merged cast: 6 segments fp32 -> bf16 (blockIdx.y selects). Seq inputs are
// 8M floats (2M float4); weights are 4M floats (1M float4) — guard per segment.
// ---------------------------------------------------------------------------
__global__ __launch_bounds__(256) void cast6(
    const float* __restrict__ i0, const float* __restrict__ i1,
    const float* __restrict__ i2, const float* __restrict__ i3,
    const float* __restrict__ i4, const float* __restrict__ i5,
    bf16* __restrict__ o0, bf16* __restrict__ o1, bf16* __restrict__ o2,
    bf16* __restrict__ o3, bf16* __restrict__ o4, bf16* __restrict__ o5) {
  const float* in;
  bf16* out;
  int n4;
  switch (blockIdx.y) {
    case 0: in = i0; out = o0; n4 = (S_SEQ * E_DIM) / 4; break;
    case 1: in = i1; out = o1; n4 = (S_SEQ * E_DIM) / 4; break;
    case 2: in = i2; out = o2; n4 = (S_SEQ * E_DIM) / 4; break;
    case 3: in = i3; out = o3; n4 = (D_DIM * E_DIM) / 4; break;
    case 4: in = i4; out = o4; n4 = (D_DIM * E_DIM) / 4; break;
    default: in = i5; out = o5; n4 = (D_DIM * E_DIM) / 4; break;
  }
  int i = blockIdx.x * 256 + threadIdx.x;
  if (i < n4) {
    float4 v = reinterpret_cast<const float4*>(in)[i];
    bf16x4 o;
    o[0] = (bf16)v.x; o[1] = (bf16)v.y; o[2] = (bf16)v.z; o[3] = (bf16)v.w;
    *reinterpret_cast<bf16x4*>(out + 4 * (size_t)i) = o;
  }
}

// ---------------------------------------------------------------------------
// async global->LDS 16B helper (wave-uniform lds base + lane*16 scatter)
// ---------------------------------------------------------------------------
__device__ __forceinline__ void async_copy16(const bf16* g, bf16* l) {
  __builtin_amdgcn_global_load_lds(
      (const __attribute__((address_space(1))) void*)g,
      (__attribute__((address_space(3))) void*)l, 16, 0, 0);
}

// XOR swizzle of the 4 16B k-chunks within a row: kills the 8-way ds_read_b128
// bank-group conflict (row stride 64B). slot col' holds k-chunk col'^swz(row).
__device__ __forceinline__ int swz(int row) {
  return (row & 3) ^ ((row >> 2) & 3);
}

// ---------------------------------------------------------------------------
// GEMM body: C[M,N] = A[M,K] @ B[N,K]^T (+ bias[n] if OUT_BF16)
// A,B bf16 row-major (lda/ldb). 128x128 tile, BK=32, 4 waves in 2x2,
// each wave 4x4 grid of mfma_f32_16x16x32_bf16.
// ---------------------------------------------------------------------------
template <bool OUT_BF16>
__device__ __forceinline__ void gemm_body(
    const bf16* __restrict__ A, int lda,
    const bf16* __restrict__ B, int ldb,
    void* __restrict__ C, int ldc,
    const float* __restrict__ bias, int K, int mBase, int nBase) {
  __shared__ __align__(16) bf16 Als[128 * 32];
  __shared__ __align__(16) bf16 Bls[128 * 32];

  const int tid  = threadIdx.x;
  const int wave = tid >> 6;
  const int lane = tid & 63;
  const int quad = lane >> 4;   // 0..3
  const int lrow = lane & 15;   // 0..15
  const int wRow = (wave >> 1) * 64;
  const int wCol = (wave & 1) * 64;

  f32x4 acc[4][4];
#pragma unroll
  for (int i = 0; i < 4; ++i)
#pragma unroll
    for (int j = 0; j < 4; ++j) {
      f32x4 z = {0.f, 0.f, 0.f, 0.f};
      acc[i][j] = z;
    }

  for (int k0 = 0; k0 < K; k0 += 32) {
    // stage A/B tiles: 128 rows x 32 cols bf16 = 8KB = 512 x 16B chunks each
#pragma unroll
    for (int c = 0; c < 2; ++c) {
      int chunk = c * 256 + tid;
      int row = chunk >> 2;
      int kq = (chunk & 3) ^ swz(row);
      const bf16* g = A + (size_t)(mBase + row) * lda + k0 + kq * 8;
      async_copy16(g, Als + (size_t)(c * 256 + wave * 64) * 8);
    }
#pragma unroll
    for (int c = 0; c < 2; ++c) {
      int chunk = c * 256 + tid;
      int row = chunk >> 2;
      int kq = (chunk & 3) ^ swz(row);
      const bf16* g = B + (size_t)(nBase + row) * ldb + k0 + kq * 8;
      async_copy16(g, Bls + (size_t)(c * 256 + wave * 64) * 8);
    }
    __syncthreads();  // drains vmcnt: LDS tiles ready

    bf16x8 af[4], bfr[4];
#pragma unroll
    for (int i = 0; i < 4; ++i) {
      int r = wRow + i * 16 + lrow;
      af[i] = *(const bf16x8*)(Als + (size_t)r * 32 + (quad ^ swz(r)) * 8);
    }
#pragma unroll
    for (int j = 0; j < 4; ++j) {
      int r = wCol + j * 16 + lrow;
      bfr[j] = *(const bf16x8*)(Bls + (size_t)r * 32 + (quad ^ swz(r)) * 8);
    }
#pragma unroll
    for (int i = 0; i < 4; ++i)
#pragma unroll
      for (int j = 0; j < 4; ++j)
        acc[i][j] = __builtin_amdgcn_mfma_f32_16x16x32_bf16(af[i], bfr[j], acc[i][j], 0, 0, 0);
    __syncthreads();  // compute done; safe to overwrite LDS next iter
  }

  // epilogue. C/D layout (verified m89/m91): col=lane&15, row=quad*4+reg
#pragma unroll
  for (int j = 0; j < 4; ++j) {
    const int cn = nBase + wCol + j * 16 + lrow;
    float bj = 0.f;
    if (OUT_BF16) bj = bias[cn];
#pragma unroll
    for (int i = 0; i < 4; ++i) {
      const int rbase = mBase + wRow + i * 16 + quad * 4;
#pragma unroll
      for (int r = 0; r < 4; ++r) {
        if (OUT_BF16)
          ((bf16*)C)[(size_t)(rbase + r) * ldc + cn] = (bf16)(acc[i][j][r] + bj);
        else
          ((float*)C)[(size_t)(rbase + r) * ldc + cn] = acc[i][j][r];
      }
    }
  }
}

// fp32-output GEMM (QK^T logits, PV output)
__global__ __launch_bounds__(256, 2) void gemm_bt_f32(
    const bf16* __restrict__ A, int lda,
    const bf16* __restrict__ B, int ldb,
    float* __restrict__ C, int ldc, int K) {
  gemm_body<false>(A, lda, B, ldb, (void*)C, ldc, nullptr, K,
                   blockIdx.y * 128, blockIdx.x * 128);
}

// merged projections: z selects (x, W, b, out); out bf16 with bias
__global__ __launch_bounds__(256, 2) void proj_gemm(
    const bf16* __restrict__ xk, const bf16* __restrict__ xq,
    const bf16* __restrict__ xv,
    const bf16* __restrict__ Wk, const bf16* __restrict__ Wq,
    const bf16* __restrict__ Wv,
    const float* __restrict__ bk, const float* __restrict__ bq,
    const float* __restrict__ bv,
    bf16* __restrict__ ok, bf16* __restrict__ oq, bf16* __restrict__ ov) {
  const bf16 *A, *W;
  const float* b;
  bf16* o;
  switch (blockIdx.z) {
    case 0: A = xk; W = Wk; b = bk; o = ok; break;
    case 1: A = xq; W = Wq; b = bq; o = oq; break;
    default: A = xv; W = Wv; b = bv; o = ov; break;
  }
  gemm_body<true>(A, E_DIM, W, E_DIM, (void*)o, D_DIM, b, E_DIM,
                  blockIdx.y * 128, blockIdx.x * 128);
}

// ---------------------------------------------------------------------------
// bf16 transpose: in[S,D] -> out[D,S], 64x64 tiles via LDS
// ---------------------------------------------------------------------------
__global__ __launch_bounds__(256) void transpose_bf16(
    const bf16* __restrict__ in, bf16* __restrict__ out) {
  __shared__ bf16 tile[64][66];
  const int t = threadIdx.x;
  const int c0 = blockIdx.x * 64;  // over D
  const int r0 = blockIdx.y * 64;  // over S
  const int col = t & 63;
  const int r4 = t >> 6;
#pragma unroll
  for (int i = 0; i < 16; ++i) {
    int rr = i * 4 + r4;
    tile[rr][col] = in[(size_t)(r0 + rr) * D_DIM + c0 + col];
  }
  __syncthreads();
#pragma unroll
  for (int i = 0; i < 16; ++i) {
    int rr = i * 4 + r4;
    out[(size_t)(c0 + rr) * S_SEQ + r0 + col] = tile[col][rr];
  }
}

// ---------------------------------------------------------------------------
// row softmax: logits fp32 [Q,S] -> P bf16 overlaid on each row's own fp32
// span (P row stride = 2*S bf16). One block per row, float4 loads.
// ---------------------------------------------------------------------------
__global__ __launch_bounds__(256) void softmax_rows(
    const float* __restrict__ logits, bf16* __restrict__ P, float scale) {
  __shared__ float red[8];
  const int r = blockIdx.x;
  const int t = threadIdx.x;
  const int wid = t >> 6;
  const int lane = t & 63;
  const float4* src4 = (const float4*)(logits + (size_t)r * S_SEQ);

  float4 v[4];
  float lmax = -3.4e38f;
#pragma unroll
  for (int i = 0; i < 4; ++i) {
    v[i] = src4[t + i * 256];
    lmax = fmaxf(fmaxf(fmaxf(lmax, v[i].x), fmaxf(v[i].y, v[i].z)), v[i].w);
  }
#pragma unroll
  for (int off = 32; off > 0; off >>= 1)
    lmax = fmaxf(lmax, __shfl_down(lmax, off, 64));
  if (lane == 0) red[wid] = lmax;
  __syncthreads();
  if (t == 0) red[4] = fmaxf(fmaxf(red[0], red[1]), fmaxf(red[2], red[3]));
  __syncthreads();
  const float rmax = red[4];

  float lsum = 0.f;
#pragma unroll
  for (int i = 0; i < 4; ++i) {
    v[i].x = __expf((v[i].x - rmax) * scale);
    v[i].y = __expf((v[i].y - rmax) * scale);
    v[i].z = __expf((v[i].z - rmax) * scale);
    v[i].w = __expf((v[i].w - rmax) * scale);
    lsum += v[i].x + v[i].y + v[i].z + v[i].w;
  }
#pragma unroll
  for (int off = 32; off > 0; off >>= 1)
    lsum += __shfl_down(lsum, off, 64);
  if (lane == 0) red[wid] = lsum;
  __syncthreads();
  if (t == 0) red[5] = red[0] + red[1] + red[2] + red[3];
  __syncthreads();
  const float inv = 1.0f / red[5];

  bf16x4* dst4 = (bf16x4*)(P + (size_t)r * (2 * S_SEQ));
#pragma unroll
  for (int i = 0; i < 4; ++i) {
    bf16x4 o;
    o[0] = (bf16)(v[i].x * inv);
    o[1] = (bf16)(v[i].y * inv);
    o[2] = (bf16)(v[i].z * inv);
    o[3] = (bf16)(v[i].w * inv);
    dst4[t + i * 256] = o;
  }
}

// ---------------------------------------------------------------------------
// launcher
// ---------------------------------------------------------------------------
extern "C" void kernel_launch(void* const* d_in, const int* in_sizes, int n_in,
                              void* d_out, int out_size, void* d_ws, size_t ws_size,
                              hipStream_t stream) {
  const float* key   = (const float*)d_in[0];
  const float* value = (const float*)d_in[1];
  const float* query = (const float*)d_in[2];
  const float* Wk = (const float*)d_in[3];
  const float* bk = (const float*)d_in[4];
  const float* Wq = (const float*)d_in[5];
  const float* bq = (const float*)d_in[6];
  const float* Wv = (const float*)d_in[7];
  const float* bv = (const float*)d_in[8];

  const size_t MB = 1ull << 20;
  char* ws = (char*)d_ws;
  // ws layout (136 MiB total):
  //   0..48Mi   : key_bf/value_bf/query_bf   (dead after projections)
  //   48..72Mi  : Wk_bf/Wq_bf/Wv_bf (8 MiB each; dead after projections)
  //   72..120Mi : k_bf / q_bf / v_bf
  //   120..136Mi: vT_bf
  //   0..64Mi   : logits fp32 (reuses cast region); P bf16 overlays rows
  bf16* key_bf   = (bf16*)(ws + 0 * MB);
  bf16* value_bf = (bf16*)(ws + 16 * MB);
  bf16* query_bf = (bf16*)(ws + 32 * MB);
  bf16* Wk_bf    = (bf16*)(ws + 48 * MB);
  bf16* Wq_bf    = (bf16*)(ws + 56 * MB);
  bf16* Wv_bf    = (bf16*)(ws + 64 * MB);
  bf16* k_bf     = (bf16*)(ws + 72 * MB);
  bf16* q_bf     = (bf16*)(ws + 88 * MB);
  bf16* v_bf     = (bf16*)(ws + 104 * MB);
  bf16* vT_bf    = (bf16*)(ws + 120 * MB);
  float* logits  = (float*)(ws + 0 * MB);
  bf16* P        = (bf16*)(ws + 0 * MB);

  dim3 blk(256);

  // 1. all six casts in one dispatch (seq: 2M float4 each; weights: 1M each)
  cast6<<<dim3(8192, 6), blk, 0, stream>>>(
      key, value, query, Wk, Wq, Wv,
      key_bf, value_bf, query_bf, Wk_bf, Wq_bf, Wv_bf);

  // 2. all three projections in one dispatch (grid.z selects k/q/v)
  proj_gemm<<<dim3(D_DIM / 128, S_SEQ / 128, 3), blk, 0, stream>>>(
      key_bf, query_bf, value_bf, Wk_bf, Wq_bf, Wv_bf, bk, bq, bv,
      k_bf, q_bf, v_bf);

  // 3. v^T for the PV GEMM
  transpose_bf16<<<dim3(D_DIM / 64, S_SEQ / 64), blk, 0, stream>>>(v_bf, vT_bf);

  // 4. logits = q @ k^T (fp32, unscaled; scale folded into softmax)
  gemm_bt_f32<<<dim3(S_SEQ / 128, Q_SEQ / 128), blk, 0, stream>>>(
      q_bf, D_DIM, k_bf, D_DIM, logits, S_SEQ, D_DIM);

  // 5. softmax rows -> P bf16 (row stride 2*S over the logits region)
  const float scale = 0.022097086912079608f;  // 1/sqrt(2048)
  softmax_rows<<<Q_SEQ, blk, 0, stream>>>(logits, P, scale);

  // 6. out = P @ v  (= P @ (vT)^T), fp32 to d_out
  gemm_bt_f32<<<dim3(D_DIM / 128, Q_SEQ / 128), blk, 0, stream>>>(
      P, 2 * S_SEQ, vT_bf, S_SEQ, (float*)d_out, D_DIM, S_SEQ);
}